// Round 2
// baseline (1128.771 us; speedup 1.0000x reference)
//
#include <hip/hip_runtime.h>

#define IN_H   1024
#define IN_W   1024
#define TILE_X 128
#define TILE_Y 64
#define LDS_H  70     // TILE_Y + 6 halo
#define LDS_W  136    // 34 float4: covers TILE_X + 6 halo + alignment slack
#define ROW_F4 34
#define STAGE_N (LDS_H * ROW_F4)   // 2380 float4 loads per block

typedef float vfloat4 __attribute__((ext_vector_type(4)));

__global__ __launch_bounds__(256, 4)
void conv7x7_kernel(const float* __restrict__ X,
                    const float* __restrict__ W,
                    float* __restrict__ out) {
    __shared__ __align__(16) float lds[LDS_H * LDS_W];

    const int tid = threadIdx.x;
    const int x0  = blockIdx.x * TILE_X;
    const int y0  = blockIdx.y * TILE_Y;
    const int b   = blockIdx.z;

    const float* Ximg = X + (size_t)b * IN_H * IN_W;

    // LDS col 0 = global col x0-4 (3-halo + 1 for float4 alignment)
    // LDS row 0 = global row y0-3
    const int gx = x0 - 4;
    const int gy = y0 - 3;

    const bool interior = (gx >= 0) && (gx + LDS_W <= IN_W) &&
                          (gy >= 0) && (gy + LDS_H <= IN_H);

    if (interior) {
        for (int idx = tid; idx < STAGE_N; idx += 256) {
            int r = idx / ROW_F4;
            int c = idx - r * ROW_F4;
            vfloat4 v = *(const vfloat4*)(Ximg + (size_t)(gy + r) * IN_W + gx + c * 4);
            *(vfloat4*)&lds[r * LDS_W + c * 4] = v;
        }
    } else {
        for (int idx = tid; idx < STAGE_N; idx += 256) {
            int r   = idx / ROW_F4;
            int c   = idx - r * ROW_F4;
            int row = gy + r;
            vfloat4 v = {0.f, 0.f, 0.f, 0.f};
            if (row >= 0 && row < IN_H) {
                const float* p = Ximg + (size_t)row * IN_W;
                int col = gx + c * 4;
                v.x = (col + 0 >= 0 && col + 0 < IN_W) ? p[col + 0] : 0.f;
                v.y = (col + 1 >= 0 && col + 1 < IN_W) ? p[col + 1] : 0.f;
                v.z = (col + 2 >= 0 && col + 2 < IN_W) ? p[col + 2] : 0.f;
                v.w = (col + 3 >= 0 && col + 3 < IN_W) ? p[col + 3] : 0.f;
            }
            *(vfloat4*)&lds[r * LDS_W + c * 4] = v;
        }
    }

    // Weights: uniform reads -> SGPRs (SGPR_Count=96 last round confirms)
    float w[49];
    #pragma unroll
    for (int k = 0; k < 49; ++k) w[k] = W[k];

    __syncthreads();

    const int tx = tid & 31;   // 32 thread-columns x 4 outputs wide = 128
    const int ty = tid >> 5;   // 8 thread-rows x 8 outputs tall = 64

    float acc[8][4];
    #pragma unroll
    for (int o = 0; o < 8; ++o)
        #pragma unroll
        for (int c = 0; c < 4; ++c) acc[o][c] = 0.f;

    const int base_col = tx * 4;

    #pragma unroll
    for (int r = 0; r < 14; ++r) {   // 14 input rows feed 8 output rows
        const float* row = &lds[(ty * 8 + r) * LDS_W + base_col];
        vfloat4 A = *(const vfloat4*)(row);
        vfloat4 B = *(const vfloat4*)(row + 4);
        vfloat4 C = *(const vfloat4*)(row + 8);
        // Keep ALL 12 dwords architecturally live so the compiler must emit
        // three aligned ds_read_b128 (dead s[0]/s[11] otherwise shrink these
        // into narrow strided LDS reads -> 4-way bank conflicts, R1 counter).
        asm volatile("" : "+v"(A), "+v"(B), "+v"(C));
        float s[12] = { A.x, A.y, A.z, A.w,
                        B.x, B.y, B.z, B.w,
                        C.x, C.y, C.z, C.w };
        #pragma unroll
        for (int o = 0; o < 8; ++o) {
            const int ky = r - o;
            if (ky >= 0 && ky < 7) {
                #pragma unroll
                for (int kx = 0; kx < 7; ++kx) {
                    const float wv = w[ky * 7 + kx];
                    #pragma unroll
                    for (int c = 0; c < 4; ++c)
                        acc[o][c] += wv * s[1 + c + kx];
                }
            }
        }
    }

    float* Oimg = out + (size_t)b * IN_H * IN_W;
    const int ox = x0 + tx * 4;
    #pragma unroll
    for (int o = 0; o < 8; ++o) {
        const int oy = y0 + ty * 8 + o;
        vfloat4 v = { acc[o][0], acc[o][1], acc[o][2], acc[o][3] };
        // Non-temporal: output is write-once, keep L2/L3 for X halo reuse.
        __builtin_nontemporal_store(v, (vfloat4*)(Oimg + (size_t)oy * IN_W + ox));
    }
}

extern "C" void kernel_launch(void* const* d_in, const int* in_sizes, int n_in,
                              void* d_out, int out_size, void* d_ws, size_t ws_size,
                              hipStream_t stream) {
    const float* X = (const float*)d_in[0];
    const float* W = (const float*)d_in[1];
    float* out = (float*)d_out;

    dim3 grid(IN_W / TILE_X, IN_H / TILE_Y, 64);
    conv7x7_kernel<<<grid, 256, 0, stream>>>(X, W, out);
}